// Round 1
// baseline (4740.174 us; speedup 1.0000x reference)
//
#include <hip/hip_runtime.h>
#include <hip/hip_fp16.h>

// Problem constants
#define ORDER   2048
#define IN_DIM  64
#define T_LEN   4096

// Chunked-scan configuration.
// J chunks of length L; warmup W. A^W ~ 0 (spectral radius ~0.4) so each
// chunk can start from h=0, W steps early. S = W + L - 1 sequential steps.
#define NCHUNK  64          // J
#define CLEN    64          // L = T_LEN / NCHUNK
#define WARM    64          // W
#define S_STEPS (WARM + CLEN - 1)   // 127

#define KSLICES 16
#define KS_LEN  (ORDER / KSLICES)   // 128

__global__ __launch_bounds__(256) void zero_kernel(float* __restrict__ p, int n) {
    int idx = blockIdx.x * 256 + threadIdx.x;
    if (idx < n) p[idx] = 0.0f;
}

// Pack two floats into one uint holding two fp16 (lo = a, hi = b).
static __device__ __forceinline__ unsigned pack2h(float a, float b) {
    __half ha = __float2half_rn(a);
    __half hb = __float2half_rn(b);
    return ((unsigned)__half_as_ushort(hb) << 16) | (unsigned)__half_as_ushort(ha);
}

// bu[t][i] = sum_d B[i][d] * u[d][t], stored fp16, layout [T_LEN][ORDER].
// Grid: (64 tau-groups, 8 i-groups), 256 threads.
// Thread (wave w, lane l): tau = t0 + l, computes 64 consecutive i's.
__global__ __launch_bounds__(256) void bu_kernel(const float* __restrict__ u,
                                                 const float* __restrict__ Bw,
                                                 ushort* __restrict__ bu) {
    __shared__ float lds_u[IN_DIM * 64];   // [d][tau_local]
    const int t0 = blockIdx.x * 64;
    const int i0 = blockIdx.y * 256;
    const int tid = threadIdx.x;
    for (int idx = tid; idx < IN_DIM * 64; idx += 256) {
        int d = idx >> 6, tt = idx & 63;
        lds_u[idx] = u[d * T_LEN + t0 + tt];
    }
    __syncthreads();
    const int w = __builtin_amdgcn_readfirstlane(tid >> 6);
    const int l = tid & 63;
    const int ib = i0 + w * 64;           // wave-uniform -> scalar B loads
    float acc[64];
#pragma unroll
    for (int s = 0; s < 64; ++s) acc[s] = 0.0f;
    for (int d = 0; d < IN_DIM; d += 4) {
        float u0 = lds_u[(d + 0) * 64 + l];
        float u1 = lds_u[(d + 1) * 64 + l];
        float u2 = lds_u[(d + 2) * 64 + l];
        float u3 = lds_u[(d + 3) * 64 + l];
#pragma unroll
        for (int s = 0; s < 64; ++s) {
            const float* br = Bw + (size_t)(ib + s) * IN_DIM + d;
            acc[s] += br[0] * u0 + br[1] * u1 + br[2] * u2 + br[3] * u3;
        }
    }
    // 64 halves = 128 B contiguous per thread; write as 8 x uint4.
    ushort* dstp = bu + (size_t)(t0 + l) * ORDER + ib;
#pragma unroll
    for (int q = 0; q < 8; ++q) {
        uint4 v;
        v.x = pack2h(acc[q * 8 + 0], acc[q * 8 + 1]);
        v.y = pack2h(acc[q * 8 + 2], acc[q * 8 + 3]);
        v.z = pack2h(acc[q * 8 + 4], acc[q * 8 + 5]);
        v.w = pack2h(acc[q * 8 + 6], acc[q * 8 + 7]);
        ((uint4*)dstp)[q] = v;
    }
}

// Partial GEMM: P[ks][j][i] = sum_{m in kslice} A[i][m] * H[m][j]
// H layout: [m][j] (m-major, 64 cols). P layout: [ks*64 + j][i] (j-major)
// so the reduce kernel reads it coalesced with lane->i.
// Grid: 512 blocks = 32 i-groups x 16 k-slices, 256 threads (4 waves x 16 rows).
__global__ __launch_bounds__(256) void gemm_kernel(const float* __restrict__ A,
                                                   const float* __restrict__ H,
                                                   float* __restrict__ P) {
    const int bx = blockIdx.x;
    const int ks = bx & (KSLICES - 1);
    const int ig = bx >> 4;
    const int tid = threadIdx.x;
    const int w = __builtin_amdgcn_readfirstlane(tid >> 6);
    const int l = tid & 63;                  // lane -> column j
    const int i0 = ig * 64 + w * 16;         // wave-uniform row base
    const int m0 = ks * KS_LEN;

    float acc[16];
#pragma unroll
    for (int r = 0; r < 16; ++r) acc[r] = 0.0f;

    for (int m = m0; m < m0 + KS_LEN; m += 4) {
        float v0 = H[(size_t)(m + 0) * NCHUNK + l];
        float v1 = H[(size_t)(m + 1) * NCHUNK + l];
        float v2 = H[(size_t)(m + 2) * NCHUNK + l];
        float v3 = H[(size_t)(m + 3) * NCHUNK + l];
#pragma unroll
        for (int r = 0; r < 16; ++r) {
            const float* ar = A + (size_t)(i0 + r) * ORDER + m;  // uniform -> s_load
            acc[r] += ar[0] * v0 + ar[1] * v1 + ar[2] * v2 + ar[3] * v3;
        }
    }

    // Transpose 64x64 tile through LDS so P writes are coalesced along i.
    __shared__ float lds_o[64 * 65];
#pragma unroll
    for (int r = 0; r < 16; ++r) lds_o[(w * 16 + r) * 65 + l] = acc[r];
    __syncthreads();
#pragma unroll
    for (int r = 0; r < 16; ++r) {
        int j = w * 16 + r;
        P[(size_t)(ks * 64 + j) * ORDER + ig * 64 + l] = lds_o[l * 65 + j];
    }
}

// Reduce partials, add bu, emit tanh output column, write next H.
// Grid: 512 = 32 i-groups x 16 j-groups, 256 threads (4 waves = 4 j's, lane->i).
__global__ __launch_bounds__(256) void reduce_kernel(const float* __restrict__ P,
                                                     const ushort* __restrict__ bu,
                                                     float* __restrict__ Hn,
                                                     float* __restrict__ out,
                                                     int k) {
    const int bx = blockIdx.x;
    const int jg = bx & 15;
    const int ig = bx >> 4;
    const int tid = threadIdx.x;
    const int w = __builtin_amdgcn_readfirstlane(tid >> 6);
    const int l = tid & 63;
    const int j = jg * 4 + w;
    const int i = ig * 64 + l;

    float s = 0.0f;
#pragma unroll
    for (int ks = 0; ks < KSLICES; ++ks)
        s += P[(size_t)(ks * 64 + j) * ORDER + i];

    const int tau = j * CLEN - WARM + k;   // time of state entering this step
    float b;
    if (tau >= 0) {
        b = __half2float(__ushort_as_half(bu[(size_t)tau * ORDER + i]));
    } else {
        b = (tau == -1) ? 1.0f : 0.0f;     // b_{-1} = ones injects h0 = 1 exactly
    }
    const float h = s + b;                 // h_{tau+1}

    if (k >= WARM - 1) {                   // emit column tau+1 (in [jL, jL+L))
        float e = __expf(-2.0f * fabsf(h));
        float o = (1.0f - e) / (1.0f + e);
        o = copysignf(o, h);
        out[(size_t)i * T_LEN + (tau + 1)] = o;
    }

    // Transpose through LDS so Hn ([m][j] layout) gets 16B stores per row.
    __shared__ float lds_t[64 * 5];
    lds_t[l * 5 + w] = h;
    __syncthreads();
    if (w == 0) {
        float4 hv;
        hv.x = lds_t[l * 5 + 0];
        hv.y = lds_t[l * 5 + 1];
        hv.z = lds_t[l * 5 + 2];
        hv.w = lds_t[l * 5 + 3];
        *(float4*)&Hn[(size_t)(ig * 64 + l) * NCHUNK + jg * 4] = hv;
    }
}

extern "C" void kernel_launch(void* const* d_in, const int* in_sizes, int n_in,
                              void* d_out, int out_size, void* d_ws, size_t ws_size,
                              hipStream_t stream) {
    const float* u  = (const float*)d_in[0];   // [IN_DIM][T_LEN]
    const float* A  = (const float*)d_in[1];   // [ORDER][ORDER]
    const float* Bw = (const float*)d_in[2];   // [ORDER][IN_DIM]
    float* out = (float*)d_out;                // [ORDER][T_LEN]

    char* ws = (char*)d_ws;
    ushort* bu = (ushort*)ws;                                   // 16.78 MB
    float* P   = (float*)(ws + (size_t)T_LEN * ORDER * 2);      //  8.39 MB
    float* Ha  = (float*)((char*)P + (size_t)KSLICES * NCHUNK * ORDER * 4);
    float* Hb  = Ha + (size_t)ORDER * NCHUNK;                   // 2 x 0.5 MB

    zero_kernel<<<dim3((ORDER * NCHUNK + 255) / 256), 256, 0, stream>>>(Ha, ORDER * NCHUNK);
    bu_kernel<<<dim3(64, 8), 256, 0, stream>>>(u, Bw, bu);

    float* Hc = Ha;
    float* Hn = Hb;
    for (int k = 0; k < S_STEPS; ++k) {
        gemm_kernel<<<dim3(512), 256, 0, stream>>>(A, Hc, P);
        reduce_kernel<<<dim3(512), 256, 0, stream>>>(P, bu, Hn, out, k);
        float* t = Hc; Hc = Hn; Hn = t;
    }
}

// Round 2
// 2965.380 us; speedup vs baseline: 1.5985x; 1.5985x over previous
//
#include <hip/hip_runtime.h>
#include <hip/hip_fp16.h>
#include <hip/hip_cooperative_groups.h>

// Problem constants
#define ORDER   2048
#define IN_DIM  64
#define T_LEN   4096

// Chunked-scan: J chunks of length L, warmup W. ||A^W|| <= 0.81^32 ~ 1e-3
// (worst case; typical spectral radius 0.4 -> 1e-13), so each chunk starts
// from h=0, W steps early. S = W + L - 1 sequential steps, all chunks in
// parallel as columns of a 2048 x J GEMM per step.
#define NCHUNK  128         // J
#define CLEN    32          // L = T_LEN / NCHUNK
#define WARM    32          // W
#define S_STEPS (WARM + CLEN - 1)   // 63

using half8v  = __attribute__((ext_vector_type(8))) _Float16;
using half4v  = __attribute__((ext_vector_type(4))) _Float16;
using float4v = __attribute__((ext_vector_type(4))) float;

__global__ __launch_bounds__(256) void zero_kernel(float* __restrict__ p, int n) {
    int idx = blockIdx.x * 256 + threadIdx.x;
    if (idx < n) p[idx] = 0.0f;
}

// bu[t][i] = sum_d B[i][d] * u[d][t], fp32, layout [T_LEN][ORDER].
// Grid: (64 tau-groups, 8 i-groups), 256 threads.
__global__ __launch_bounds__(256) void bu_kernel(const float* __restrict__ u,
                                                 const float* __restrict__ Bw,
                                                 float* __restrict__ bu) {
    __shared__ float lds_u[IN_DIM * 64];   // [d][tau_local]
    const int t0 = blockIdx.x * 64;
    const int i0 = blockIdx.y * 256;
    const int tid = threadIdx.x;
    for (int idx = tid; idx < IN_DIM * 64; idx += 256) {
        int d = idx >> 6, tt = idx & 63;
        lds_u[idx] = u[d * T_LEN + t0 + tt];
    }
    __syncthreads();
    const int w = __builtin_amdgcn_readfirstlane(tid >> 6);
    const int l = tid & 63;
    const int ib = i0 + w * 64;           // wave-uniform -> scalar B loads
    float acc[64];
#pragma unroll
    for (int s = 0; s < 64; ++s) acc[s] = 0.0f;
    for (int d = 0; d < IN_DIM; d += 4) {
        float u0 = lds_u[(d + 0) * 64 + l];
        float u1 = lds_u[(d + 1) * 64 + l];
        float u2 = lds_u[(d + 2) * 64 + l];
        float u3 = lds_u[(d + 3) * 64 + l];
#pragma unroll
        for (int s = 0; s < 64; ++s) {
            const float* br = Bw + (size_t)(ib + s) * IN_DIM + d;
            acc[s] += br[0] * u0 + br[1] * u1 + br[2] * u2 + br[3] * u3;
        }
    }
    float* dstp = bu + (size_t)(t0 + l) * ORDER + ib;
#pragma unroll
    for (int q = 0; q < 16; ++q) {
        float4v v = {acc[q * 4 + 0], acc[q * 4 + 1], acc[q * 4 + 2], acc[q * 4 + 3]};
        ((float4v*)dstp)[q] = v;
    }
}

// Pack A (fp32 row-major) into fp16 MFMA A-fragment order:
// block (R, c) of 1024 B: lane l holds A[R*16 + (l&15)][c*32 + (l>>4)*8 + j], j=0..7.
// Consumer load is then a single perfectly-coalesced dwordx4 per lane.
__global__ __launch_bounds__(256) void pack_kernel(const float* __restrict__ A,
                                                   _Float16* __restrict__ Ap) {
    int tid = blockIdx.x * 256 + threadIdx.x;   // 0 .. 128*64*64-1
    int l = tid & 63;
    int c = (tid >> 6) & 63;
    int R = tid >> 12;
    int row = R * 16 + (l & 15);
    int col = c * 32 + (l >> 4) * 8;
    const float4v* src = (const float4v*)(A + (size_t)row * ORDER + col);
    float4v f0 = src[0], f1 = src[1];
    half8v h;
    h[0] = (_Float16)f0[0]; h[1] = (_Float16)f0[1];
    h[2] = (_Float16)f0[2]; h[3] = (_Float16)f0[3];
    h[4] = (_Float16)f1[0]; h[5] = (_Float16)f1[1];
    h[6] = (_Float16)f1[2]; h[7] = (_Float16)f1[3];
    ((half8v*)Ap)[tid] = h;
}

// Persistent cooperative step kernel.
// 256 wg x 256 thr (4 waves). Output 2048 x J tiled 32x32: 64 row-blocks x 4
// col-blocks. XCD-aware: wg%8 = XCD owns a 256-row slab -> A footprint 1 MB/XCD
// stays L2-resident. Each wave: one 16x16 quadrant, full K=2048 (64 MFMAs).
// Ht (state) is [j][m] fp16, double-buffered; one grid.sync per step.
__global__ __launch_bounds__(256) void step_kernel(const _Float16* __restrict__ Ap,
                                                   const float* __restrict__ bu,
                                                   _Float16* __restrict__ Ha,
                                                   _Float16* __restrict__ Hb,
                                                   float* __restrict__ out) {
    const int w   = blockIdx.x;          // 0..255
    const int xcd = w & 7;
    const int s   = w >> 3;              // 0..31
    const int rb  = xcd * 8 + (s & 7);   // row-block (32 rows), 0..63
    const int cb  = s >> 3;              // col-block (32 cols), 0..3
    const int tid  = threadIdx.x;
    const int wave = tid >> 6;
    const int l    = tid & 63;
    const int wr = wave & 1, wc = wave >> 1;
    const int i0 = rb * 32 + wr * 16;    // quadrant row base (i / m dim)
    const int j0 = cb * 32 + wc * 16;    // quadrant col base (j / chunk dim)
    const int n    = l & 15;
    const int quad = l >> 4;
    const int R = i0 >> 4;               // 16-row block index

    // A fragments for this wave: apb[c*64 + l], c = 0..63 K-chunks.
    const half8v* __restrict__ apb = (const half8v*)(Ap + (size_t)R * 32768);

    cooperative_groups::grid_group grid = cooperative_groups::this_grid();

    for (int k = 0; k < S_STEPS; ++k) {
        const _Float16* __restrict__ Hc = (k & 1) ? Hb : Ha;
        _Float16* __restrict__       Hn = (k & 1) ? Ha : Hb;

        // B fragments: Ht[j0+n][c*32 + quad*8 + 0..8) -> contiguous 16 B.
        const half8v* __restrict__ ha =
            (const half8v*)(Hc + (size_t)(j0 + n) * ORDER) + quad;

        float4v acc[4];
        acc[0] = {0.f, 0.f, 0.f, 0.f};
        acc[1] = {0.f, 0.f, 0.f, 0.f};
        acc[2] = {0.f, 0.f, 0.f, 0.f};
        acc[3] = {0.f, 0.f, 0.f, 0.f};
#pragma unroll 8
        for (int c = 0; c < 64; ++c) {
            half8v av = apb[c * 64 + l];
            half8v bv = ha[c * 4];
            acc[c & 3] = __builtin_amdgcn_mfma_f32_16x16x32_f16(av, bv, acc[c & 3], 0, 0, 0);
        }
        float4v hs = (acc[0] + acc[1]) + (acc[2] + acc[3]);

        // Epilogue: h_new = A*h + bu_t.  C-layout: col(j)=lane&15, row(i)=quad*4+r.
        const int j = j0 + n;                 // global chunk id
        const int t = j * CLEN - WARM + k;    // time of state entering this step
        float4v bv4;
        if (t >= 0) {
            bv4 = *(const float4v*)(bu + (size_t)t * ORDER + i0 + quad * 4);
        } else {
            float v = (t == -1) ? 1.0f : 0.0f;   // bu_{-1}=1 injects h0=1 exactly
            bv4 = {v, v, v, v};
        }
        float4v h = hs + bv4;

        // Store next state: Ht_next[j][i0+quad*4 .. +4) — 8 B contiguous.
        half4v hh;
        hh[0] = (_Float16)h[0]; hh[1] = (_Float16)h[1];
        hh[2] = (_Float16)h[2]; hh[3] = (_Float16)h[3];
        *(half4v*)(Hn + (size_t)j * ORDER + i0 + quad * 4) = hh;

        // Emit output column t+1 = h_{t+1} once inside the chunk window.
        if (k >= WARM - 1) {
            const int t1 = t + 1;
#pragma unroll
            for (int r = 0; r < 4; ++r) {
                float x = h[r];
                float e = __expf(-2.0f * fabsf(x));
                float o = (1.0f - e) / (1.0f + e);
                o = copysignf(o, x);
                out[(size_t)(i0 + quad * 4 + r) * T_LEN + t1] = o;
            }
        }
        grid.sync();
    }
}

extern "C" void kernel_launch(void* const* d_in, const int* in_sizes, int n_in,
                              void* d_out, int out_size, void* d_ws, size_t ws_size,
                              hipStream_t stream) {
    const float* u  = (const float*)d_in[0];   // [IN_DIM][T_LEN]
    const float* A  = (const float*)d_in[1];   // [ORDER][ORDER]
    const float* Bw = (const float*)d_in[2];   // [ORDER][IN_DIM]
    float* out = (float*)d_out;                // [ORDER][T_LEN]

    char* ws = (char*)d_ws;
    float*     bu = (float*)ws;                                  // 33.55 MB
    _Float16*  Ap = (_Float16*)(ws + (size_t)T_LEN * ORDER * 4); //  8.39 MB
    _Float16*  Ha = (_Float16*)(ws + (size_t)T_LEN * ORDER * 4
                                   + (size_t)ORDER * ORDER * 2); //  0.5 MB
    _Float16*  Hb = Ha + (size_t)NCHUNK * ORDER;                 //  0.5 MB

    // Zero initial state (ws is poisoned 0xAA before every call).
    zero_kernel<<<dim3((NCHUNK * ORDER / 2 + 255) / 256), 256, 0, stream>>>(
        (float*)Ha, NCHUNK * ORDER / 2);
    bu_kernel<<<dim3(64, 8), 256, 0, stream>>>(u, Bw, bu);
    pack_kernel<<<dim3(2048), 256, 0, stream>>>(A, Ap);

    void* args[] = {(void*)&Ap, (void*)&bu, (void*)&Ha, (void*)&Hb, (void*)&out};
    hipLaunchCooperativeKernel((void*)step_kernel, dim3(256), dim3(256), args, 0, stream);
}

// Round 3
// 1868.491 us; speedup vs baseline: 2.5369x; 1.5870x over previous
//
#include <hip/hip_runtime.h>
#include <hip/hip_fp16.h>

// Problem constants
#define ORDER   2048
#define IN_DIM  64
#define T_LEN   4096

// Chunked-scan: J chunks of length L, warmup W. ||A^W|| ~ rho^32 << 1e-6
// (rho ~ 0.4; round-1/2 measurements confirm truncation error invisible at
// W=32), so each chunk starts from h=0, W steps early. S = W + L - 1
// sequential steps, all chunks in parallel as columns of a 2048 x J GEMM.
#define NCHUNK  128         // J
#define CLEN    32          // L = T_LEN / NCHUNK
#define WARM    32          // W
#define S_STEPS (WARM + CLEN - 1)   // 63
#define NWG     256

using half8v  = __attribute__((ext_vector_type(8))) _Float16;
using half4v  = __attribute__((ext_vector_type(4))) _Float16;
using float4v = __attribute__((ext_vector_type(4))) float;

__global__ __launch_bounds__(256) void zero_kernel(float* __restrict__ p, int n) {
    int idx = blockIdx.x * 256 + threadIdx.x;
    if (idx < n) p[idx] = 0.0f;
}

__global__ __launch_bounds__(64) void init_barrier_kernel(unsigned* __restrict__ bar) {
    if (threadIdx.x < 64) bar[threadIdx.x] = 0u;   // counter line + flag line
}

// bu[t][i] = sum_d B[i][d] * u[d][t], fp32, layout [T_LEN][ORDER].
__global__ __launch_bounds__(256) void bu_kernel(const float* __restrict__ u,
                                                 const float* __restrict__ Bw,
                                                 float* __restrict__ bu) {
    __shared__ float lds_u[IN_DIM * 64];   // [d][tau_local]
    const int t0 = blockIdx.x * 64;
    const int i0 = blockIdx.y * 256;
    const int tid = threadIdx.x;
    for (int idx = tid; idx < IN_DIM * 64; idx += 256) {
        int d = idx >> 6, tt = idx & 63;
        lds_u[idx] = u[d * T_LEN + t0 + tt];
    }
    __syncthreads();
    const int w = __builtin_amdgcn_readfirstlane(tid >> 6);
    const int l = tid & 63;
    const int ib = i0 + w * 64;           // wave-uniform -> scalar B loads
    float acc[64];
#pragma unroll
    for (int s = 0; s < 64; ++s) acc[s] = 0.0f;
    for (int d = 0; d < IN_DIM; d += 4) {
        float u0 = lds_u[(d + 0) * 64 + l];
        float u1 = lds_u[(d + 1) * 64 + l];
        float u2 = lds_u[(d + 2) * 64 + l];
        float u3 = lds_u[(d + 3) * 64 + l];
#pragma unroll
        for (int s = 0; s < 64; ++s) {
            const float* br = Bw + (size_t)(ib + s) * IN_DIM + d;
            acc[s] += br[0] * u0 + br[1] * u1 + br[2] * u2 + br[3] * u3;
        }
    }
    float* dstp = bu + (size_t)(t0 + l) * ORDER + ib;
#pragma unroll
    for (int q = 0; q < 16; ++q) {
        float4v v = {acc[q * 4 + 0], acc[q * 4 + 1], acc[q * 4 + 2], acc[q * 4 + 3]};
        ((float4v*)dstp)[q] = v;
    }
}

// Pack A (fp32 row-major) into fp16 MFMA A-fragment order:
// block (R, c) of 1024 B: lane l holds A[R*16 + (l&15)][c*32 + (l>>4)*8 + j].
__global__ __launch_bounds__(256) void pack_kernel(const float* __restrict__ A,
                                                   _Float16* __restrict__ Ap) {
    int tid = blockIdx.x * 256 + threadIdx.x;   // 0 .. 128*64*64-1
    int l = tid & 63;
    int c = (tid >> 6) & 63;
    int R = tid >> 12;
    int row = R * 16 + (l & 15);
    int col = c * 32 + (l >> 4) * 8;
    const float4v* src = (const float4v*)(A + (size_t)row * ORDER + col);
    float4v f0 = src[0], f1 = src[1];
    half8v h;
    h[0] = (_Float16)f0[0]; h[1] = (_Float16)f0[1];
    h[2] = (_Float16)f0[2]; h[3] = (_Float16)f0[3];
    h[4] = (_Float16)f1[0]; h[5] = (_Float16)f1[1];
    h[6] = (_Float16)f1[2]; h[7] = (_Float16)f1[3];
    ((half8v*)Ap)[tid] = h;
}

// Fast grid barrier: monotone arrival counter + monotone release flag.
// bar[0] = counter, bar[32] = flag (separate 128B lines). Requires all NWG
// workgroups co-resident (cooperative launch guarantees this).
static __device__ __forceinline__ void grid_barrier(unsigned* __restrict__ bar, int k) {
    __syncthreads();                       // all wg stores drained to L2
    if (threadIdx.x == 0) {
        __threadfence();                   // release: L2 -> coherent point
        unsigned want = (unsigned)(k + 1);
        unsigned old = __hip_atomic_fetch_add(&bar[0], 1u, __ATOMIC_RELAXED,
                                              __HIP_MEMORY_SCOPE_AGENT);
        if (old + 1 == want * NWG) {
            __hip_atomic_store(&bar[32], want, __ATOMIC_RELEASE,
                               __HIP_MEMORY_SCOPE_AGENT);
        } else {
            while (__hip_atomic_load(&bar[32], __ATOMIC_RELAXED,
                                     __HIP_MEMORY_SCOPE_AGENT) < want)
                __builtin_amdgcn_s_sleep(2);
        }
        __threadfence();                   // acquire: invalidate stale lines
    }
    __syncthreads();
}

// Persistent step kernel. 256 wg x 256 thr (4 waves). Output 2048 x J tiled
// 32x32: 64 row-blocks x 4 col-blocks. XCD-aware: wg%8 = XCD owns a 256-row
// slab -> A footprint 1 MB/XCD stays L2-resident. Each wave: one 16x16
// quadrant, full K=2048 (64 MFMAs). Ht is [j][m] fp16, double-buffered.
__global__ __launch_bounds__(256) void step_kernel(const _Float16* __restrict__ Ap,
                                                   const float* __restrict__ bu,
                                                   _Float16* __restrict__ Ha,
                                                   _Float16* __restrict__ Hb,
                                                   float* __restrict__ out,
                                                   unsigned* __restrict__ bar) {
    const int w   = blockIdx.x;          // 0..255
    const int xcd = w & 7;
    const int s   = w >> 3;              // 0..31
    const int rb  = xcd * 8 + (s & 7);   // row-block (32 rows), 0..63
    const int cb  = s >> 3;              // col-block (32 cols), 0..3
    const int tid  = threadIdx.x;
    const int wave = tid >> 6;
    const int l    = tid & 63;
    const int wr = wave & 1, wc = wave >> 1;
    const int i0 = rb * 32 + wr * 16;    // quadrant row base (i / m dim)
    const int j0 = cb * 32 + wc * 16;    // quadrant col base (j / chunk dim)
    const int n    = l & 15;
    const int quad = l >> 4;
    const int R = i0 >> 4;               // 16-row block index

    // A fragments for this wave: apb[c*64 + l], c = 0..63 K-chunks.
    const half8v* __restrict__ apb = (const half8v*)(Ap + (size_t)R * 32768);

    for (int k = 0; k < S_STEPS; ++k) {
        const _Float16* __restrict__ Hc = (k & 1) ? Hb : Ha;
        _Float16* __restrict__       Hn = (k & 1) ? Ha : Hb;

        // B fragments: Ht[j0+n][c*32 + quad*8 + 0..8) -> contiguous 16 B.
        const half8v* __restrict__ ha =
            (const half8v*)(Hc + (size_t)(j0 + n) * ORDER) + quad;

        float4v acc[4];
        acc[0] = {0.f, 0.f, 0.f, 0.f};
        acc[1] = {0.f, 0.f, 0.f, 0.f};
        acc[2] = {0.f, 0.f, 0.f, 0.f};
        acc[3] = {0.f, 0.f, 0.f, 0.f};
#pragma unroll 8
        for (int c = 0; c < 64; ++c) {
            half8v av = apb[c * 64 + l];
            half8v bv = ha[c * 4];
            acc[c & 3] = __builtin_amdgcn_mfma_f32_16x16x32_f16(av, bv, acc[c & 3], 0, 0, 0);
        }
        float4v hs = (acc[0] + acc[1]) + (acc[2] + acc[3]);

        // Epilogue: h_new = A*h + bu_t.  C-layout: col(j)=lane&15, row(i)=quad*4+r.
        const int j = j0 + n;                 // global chunk id
        const int t = j * CLEN - WARM + k;    // time of state entering this step
        float4v bv4;
        if (t >= 0) {
            bv4 = *(const float4v*)(bu + (size_t)t * ORDER + i0 + quad * 4);
        } else {
            float v = (t == -1) ? 1.0f : 0.0f;   // bu_{-1}=1 injects h0=1 exactly
            bv4 = {v, v, v, v};
        }
        float4v h = hs + bv4;

        // Store next state: Ht_next[j][i0+quad*4 .. +4) — 8 B contiguous.
        half4v hh;
        hh[0] = (_Float16)h[0]; hh[1] = (_Float16)h[1];
        hh[2] = (_Float16)h[2]; hh[3] = (_Float16)h[3];
        *(half4v*)(Hn + (size_t)j * ORDER + i0 + quad * 4) = hh;

        // Emit output column t+1 = h_{t+1} once inside the chunk window.
        if (k >= WARM - 1) {
            const int t1 = t + 1;
#pragma unroll
            for (int r = 0; r < 4; ++r) {
                float x = h[r];
                float e = __expf(-2.0f * fabsf(x));
                float o = (1.0f - e) / (1.0f + e);
                o = copysignf(o, x);
                out[(size_t)(i0 + quad * 4 + r) * T_LEN + t1] = o;
            }
        }

        if (k != S_STEPS - 1) grid_barrier(bar, k);
    }
}

extern "C" void kernel_launch(void* const* d_in, const int* in_sizes, int n_in,
                              void* d_out, int out_size, void* d_ws, size_t ws_size,
                              hipStream_t stream) {
    const float* u  = (const float*)d_in[0];   // [IN_DIM][T_LEN]
    const float* A  = (const float*)d_in[1];   // [ORDER][ORDER]
    const float* Bw = (const float*)d_in[2];   // [ORDER][IN_DIM]
    float* out = (float*)d_out;                // [ORDER][T_LEN]

    char* ws = (char*)d_ws;
    float*     bu = (float*)ws;                                  // 33.55 MB
    _Float16*  Ap = (_Float16*)(ws + (size_t)T_LEN * ORDER * 4); //  8.39 MB
    _Float16*  Ha = (_Float16*)(ws + (size_t)T_LEN * ORDER * 4
                                   + (size_t)ORDER * ORDER * 2); //  0.5 MB
    _Float16*  Hb = Ha + (size_t)NCHUNK * ORDER;                 //  0.5 MB
    unsigned*  bar = (unsigned*)(Hb + (size_t)NCHUNK * ORDER);   //  256 B

    zero_kernel<<<dim3((NCHUNK * ORDER / 2 + 255) / 256), 256, 0, stream>>>(
        (float*)Ha, NCHUNK * ORDER / 2);
    init_barrier_kernel<<<dim3(1), 64, 0, stream>>>(bar);
    bu_kernel<<<dim3(64, 8), 256, 0, stream>>>(u, Bw, bu);
    pack_kernel<<<dim3(2048), 256, 0, stream>>>(A, Ap);

    void* args[] = {(void*)&Ap, (void*)&bu, (void*)&Ha, (void*)&Hb,
                    (void*)&out, (void*)&bar};
    hipLaunchCooperativeKernel((void*)step_kernel, dim3(NWG), dim3(256), args, 0, stream);
}

// Round 6
// 1220.789 us; speedup vs baseline: 3.8829x; 1.5306x over previous
//
#include <hip/hip_runtime.h>
#include <hip/hip_fp16.h>

// Problem constants
#define ORDER   2048
#define IN_DIM  64
#define T_LEN   4096

// Chunked-scan: J chunks of length L, warmup W. ||A^W|| << 1 (spectral
// radius ~0.4; W=32 verified rounds 1-3, absmax 0.0039), so each chunk
// starts from h=0, W steps early. S = W + L - 1 sequential steps; all 128
// chunks advance in parallel as columns of a 2048 x 128 GEMM per step.
#define NCHUNK  128         // J
#define CLEN    32          // L = T_LEN / NCHUNK
#define WARM    32          // W
#define S_STEPS (WARM + CLEN - 1)   // 63
#define NWG     256

typedef unsigned long long ull;
using half8v  = __attribute__((ext_vector_type(8))) _Float16;
using half4v  = __attribute__((ext_vector_type(4))) _Float16;
using float4v = __attribute__((ext_vector_type(4))) float;

__global__ __launch_bounds__(256) void zero_kernel(float* __restrict__ p, int n) {
    int idx = blockIdx.x * 256 + threadIdx.x;
    if (idx < n) p[idx] = 0.0f;
}

__global__ __launch_bounds__(64) void init_barrier_kernel(unsigned* __restrict__ bar) {
    bar[threadIdx.x] = 0u;   // counter line @0, flag line @32
}

// bu[t][i] = sum_d B[i][d] * u[d][t], fp32, layout [T_LEN][ORDER]. (r2/r3-verified)
__global__ __launch_bounds__(256) void bu_kernel(const float* __restrict__ u,
                                                 const float* __restrict__ Bw,
                                                 float* __restrict__ bu) {
    __shared__ float lds_u[IN_DIM * 64];   // [d][tau_local]
    const int t0 = blockIdx.x * 64;
    const int i0 = blockIdx.y * 256;
    const int tid = threadIdx.x;
    for (int idx = tid; idx < IN_DIM * 64; idx += 256) {
        int d = idx >> 6, tt = idx & 63;
        lds_u[idx] = u[d * T_LEN + t0 + tt];
    }
    __syncthreads();
    const int w = __builtin_amdgcn_readfirstlane(tid >> 6);
    const int l = tid & 63;
    const int ib = i0 + w * 64;           // wave-uniform -> scalar B loads
    float acc[64];
#pragma unroll
    for (int s = 0; s < 64; ++s) acc[s] = 0.0f;
    for (int d = 0; d < IN_DIM; d += 4) {
        float u0 = lds_u[(d + 0) * 64 + l];
        float u1 = lds_u[(d + 1) * 64 + l];
        float u2 = lds_u[(d + 2) * 64 + l];
        float u3 = lds_u[(d + 3) * 64 + l];
#pragma unroll
        for (int s = 0; s < 64; ++s) {
            const float* br = Bw + (size_t)(ib + s) * IN_DIM + d;
            acc[s] += br[0] * u0 + br[1] * u1 + br[2] * u2 + br[3] * u3;
        }
    }
    float* dstp = bu + (size_t)(t0 + l) * ORDER + ib;
#pragma unroll
    for (int q = 0; q < 16; ++q) {
        float4v v = {acc[q * 4 + 0], acc[q * 4 + 1], acc[q * 4 + 2], acc[q * 4 + 3]};
        ((float4v*)dstp)[q] = v;
    }
}

// Pack A (fp32 row-major) into fp16 MFMA A-fragment order (r2/r3-verified):
// ((half8v*)Ap)[R*4096 + c*64 + l] = A[R*16 + (l&15)][c*32 + (l>>4)*8 .. +8].
__global__ __launch_bounds__(256) void pack_kernel(const float* __restrict__ A,
                                                   _Float16* __restrict__ Ap) {
    int tid = blockIdx.x * 256 + threadIdx.x;   // 0 .. 128*64*64-1
    int l = tid & 63;
    int c = (tid >> 6) & 63;
    int R = tid >> 12;
    int row = R * 16 + (l & 15);
    int col = c * 32 + (l >> 4) * 8;
    const float4v* src = (const float4v*)(A + (size_t)row * ORDER + col);
    float4v f0 = src[0], f1 = src[1];
    half8v h;
    h[0] = (_Float16)f0[0]; h[1] = (_Float16)f0[1];
    h[2] = (_Float16)f0[2]; h[3] = (_Float16)f0[3];
    h[4] = (_Float16)f1[0]; h[5] = (_Float16)f1[1];
    h[6] = (_Float16)f1[2]; h[7] = (_Float16)f1[3];
    ((half8v*)Ap)[tid] = h;
}

// Fence-free flat grid barrier (r3 structure minus the two __threadfence()).
// Monotone counter+flag, all RELAXED agent-scope (RMWs execute at the MALL).
// Ordering: __syncthreads drains vmcnt (compiler emits s_waitcnt vmcnt(0)
// before s_barrier), so every wave's H exchanges are globally visible before
// thread 0 signals arrival. Readers use L2-bypass loads, so no invalidate is
// needed on the acquire side.
static __device__ __forceinline__ void grid_barrier(unsigned* __restrict__ bar,
                                                    unsigned want) {
    __syncthreads();
    if (threadIdx.x == 0) {
        unsigned old = __hip_atomic_fetch_add(&bar[0], 1u, __ATOMIC_RELAXED,
                                              __HIP_MEMORY_SCOPE_AGENT);
        if (old + 1u == want * NWG) {
            (void)__hip_atomic_exchange(&bar[32], want, __ATOMIC_RELAXED,
                                        __HIP_MEMORY_SCOPE_AGENT);
        } else {
            while (__hip_atomic_load(&bar[32], __ATOMIC_RELAXED,
                                     __HIP_MEMORY_SCOPE_AGENT) < want)
                __builtin_amdgcn_s_sleep(1);
        }
        __atomic_signal_fence(__ATOMIC_ACQUIRE);
    }
    __syncthreads();
}

// Persistent step kernel — resource-light (target ~90 VGPR, 32 KB LDS so the
// cooperative occupancy check passes with large margin, like r2/r3 did).
// Tiling: 128 row-blocks (16 rows) x 8 j-groups (16 chunks); wg = 4 waves =
// 4 consecutive row-blocks sharing one LDS-staged j-panel (staged in two
// 32 KB K-halves). A is read per step as coalesced 16-B fragment loads —
// with no cache invalidates it stays L2-resident (1 MB slab per XCD).
// H lives in double buffers in B-fragment granule order; stores are 8-B
// agent-scope atomic exchanges (RMW at the MALL => cross-XCD coherent),
// staging reads are coalesced 8-B agent-scope (L2-bypass) loads.
__global__ __launch_bounds__(256) void step_kernel(const _Float16* __restrict__ Ap,
                                                   const float* __restrict__ bu,
                                                   _Float16* __restrict__ Ha,
                                                   _Float16* __restrict__ Hb,
                                                   float* __restrict__ out,
                                                   unsigned* __restrict__ bar) {
    const int w    = blockIdx.x;         // 0..255
    const int xcd  = w & 7;              // MI355X blockIdx%8 -> XCD (perf only)
    const int idx  = w >> 3;             // 0..31
    const int rg   = xcd * 4 + (idx & 3);// 64-row group: 256-row slab per XCD
    const int jg   = idx >> 2;           // 0..7: 16-chunk j-panel
    const int tid  = threadIdx.x;
    const int wave = tid >> 6;           // 0..3 -> row-block within group
    const int l    = tid & 63;
    const int n    = l & 15;
    const int quad = l >> 4;
    const int R    = rg * 4 + wave;      // global 16-row block, 0..127
    const int i0   = R * 16;
    const int j    = jg * 16 + n;        // this lane's chunk id
    const int mrow = i0 + quad * 4;

    __shared__ ull lds_h[4096];          // 32 KB: half of the j-panel

    // A fragments for this wave (coalesced 16-B loads, L2-resident).
    const half8v* __restrict__ apb = ((const half8v*)Ap) + (size_t)R * 4096 + l;

    // H-store granule within panel jg (B-fragment order): halves
    // (chunk j, m = mrow..mrow+4) -> granule (c*64 + quad(m)*16 + n)*2 + s(m).
    const int granH = (((mrow >> 5) * 64) + (((mrow >> 3) & 3) * 16) + n) * 2
                    + ((mrow >> 2) & 1);

    for (int k = 0; k < S_STEPS; ++k) {
        const ull* __restrict__ src =
            ((const ull*)((k & 1) ? Hb : Ha)) + jg * 8192;
        ull* __restrict__ dst =
            ((ull*)((k & 1) ? Ha : Hb)) + jg * 8192;

        float4v acc[2];
        acc[0] = {0.f, 0.f, 0.f, 0.f};
        acc[1] = {0.f, 0.f, 0.f, 0.f};

#pragma unroll
        for (int half = 0; half < 2; ++half) {
            // Stage 32 KB (K-chunks half*32 .. +32) into LDS: linear copy,
            // consecutive threads -> consecutive granules (coalesced bypass).
            const ull* __restrict__ sh = src + half * 4096;
#pragma unroll 4
            for (int q = 0; q < 16; ++q) {
                int g = q * 256 + tid;
                lds_h[g] = __hip_atomic_load(sh + g, __ATOMIC_RELAXED,
                                             __HIP_MEMORY_SCOPE_AGENT);
            }
            __syncthreads();

            // 32 MFMAs over this K-half (A from L2, B from LDS).
            const half8v* __restrict__ lb = ((const half8v*)lds_h) + l;
            const half8v* __restrict__ ap = apb + half * 32 * 64;
#pragma unroll 8
            for (int c = 0; c < 32; ++c) {
                half8v av = ap[c * 64];      // global 16-B coalesced (L2 hit)
                half8v bv = lb[c * 64];      // ds_read_b128, conflict-free
                acc[c & 1] = __builtin_amdgcn_mfma_f32_16x16x32_f16(av, bv, acc[c & 1], 0, 0, 0);
            }
            __syncthreads();                 // LDS reused by next half / next step
        }
        float4v hs = acc[0] + acc[1];

        // ---- Epilogue: h = A*h + bu_t (C-layout: col j = lane&15, row = quad*4+r)
        const int t = j * CLEN - WARM + k;
        float4v bv4;
        if (t >= 0) {
            bv4 = *(const float4v*)(bu + (size_t)t * ORDER + mrow);  // plain, L2
        } else {
            float v = (t == -1) ? 1.0f : 0.0f;   // bu_{-1}=1 injects h0=1 exactly
            bv4 = {v, v, v, v};
        }
        float4v h = hs + bv4;

        // Next state: atomic EXCHANGE (RMW executes at the MALL -> coherent
        // without any fence/flush). 8 B per lane, coalesced.
        union { half4v hh; ull u; } cv;
        cv.hh[0] = (_Float16)h[0]; cv.hh[1] = (_Float16)h[1];
        cv.hh[2] = (_Float16)h[2]; cv.hh[3] = (_Float16)h[3];
        (void)__hip_atomic_exchange(dst + granH, cv.u, __ATOMIC_RELAXED,
                                    __HIP_MEMORY_SCOPE_AGENT);

        // Emit output column t+1 once inside the chunk window (plain stores;
        // made host-visible by the end-of-kernel release).
        if (k >= WARM - 1) {
            const int t1 = t + 1;
#pragma unroll
            for (int r = 0; r < 4; ++r) {
                float x = h[r];
                float e = __expf(-2.0f * fabsf(x));
                float o = copysignf((1.0f - e) / (1.0f + e), x);
                out[(size_t)(mrow + r) * T_LEN + t1] = o;
            }
        }

        if (k != S_STEPS - 1) grid_barrier(bar, (unsigned)(k + 1));
    }
}

extern "C" void kernel_launch(void* const* d_in, const int* in_sizes, int n_in,
                              void* d_out, int out_size, void* d_ws, size_t ws_size,
                              hipStream_t stream) {
    const float* u  = (const float*)d_in[0];   // [IN_DIM][T_LEN]
    const float* A  = (const float*)d_in[1];   // [ORDER][ORDER]
    const float* Bw = (const float*)d_in[2];   // [ORDER][IN_DIM]
    float* out = (float*)d_out;                // [ORDER][T_LEN]

    char* ws = (char*)d_ws;
    float*     bu  = (float*)ws;                                 // 33,554,432 B
    _Float16*  Ap  = (_Float16*)(ws + 33554432);                 //  8,388,608 B
    _Float16*  Ha  = (_Float16*)(ws + 41943040);                 //    524,288 B
    _Float16*  Hb  = (_Float16*)(ws + 42467328);                 //    524,288 B
    unsigned*  bar = (unsigned*)(ws + 42991616);                 //        256 B

    // H_0 = zeros in Ha (ws is poisoned 0xAA before every call).
    zero_kernel<<<dim3(512), 256, 0, stream>>>((float*)Ha, NCHUNK * ORDER / 2);
    init_barrier_kernel<<<dim3(1), 64, 0, stream>>>(bar);
    bu_kernel<<<dim3(64, 8), 256, 0, stream>>>(u, Bw, bu);
    pack_kernel<<<dim3(2048), 256, 0, stream>>>(A, Ap);

    void* args[] = {(void*)&Ap, (void*)&bu, (void*)&Ha, (void*)&Hb,
                    (void*)&out, (void*)&bar};
    hipLaunchCooperativeKernel((void*)step_kernel, dim3(NWG), dim3(256), args, 0, stream);
}

// Round 8
// 1101.194 us; speedup vs baseline: 4.3046x; 1.1086x over previous
//
#include <hip/hip_runtime.h>
#include <hip/hip_fp16.h>

// Problem constants
#define ORDER   2048
#define IN_DIM  64
#define T_LEN   4096

// Chunked-scan: J chunks of length L, warmup W. ||A^W|| << 1 (spectral
// radius ~0.4; W=32 verified rounds 1-3/6, absmax 0.0039), so each chunk
// starts from h=0, W steps early. S = W + L - 1 sequential steps; all 128
// chunks advance in parallel as columns of a 2048 x 128 GEMM per step.
#define NCHUNK  128         // J
#define CLEN    32          // L = T_LEN / NCHUNK
#define WARM    32          // W
#define S_STEPS (WARM + CLEN - 1)   // 63
#define NWG     256

// LAUNCH-ENVELOPE NOTE (r4/r5/r7 post-mortem): hipLaunchCooperativeKernel
// silently rejects resource-heavy profiles. Proven-working: 32 KB LDS /
// ~44-70 VGPR (r6). Failed: 49 KB LDS (r7), 64 KB LDS + ~300 VGPR (r4/r5).
// step_kernel must stay at <= 32 KB static LDS and moderate VGPR.

typedef unsigned long long ull;
using half8v  = __attribute__((ext_vector_type(8))) _Float16;
using half4v  = __attribute__((ext_vector_type(4))) _Float16;
using float4v = __attribute__((ext_vector_type(4))) float;

__global__ __launch_bounds__(256) void zero_kernel(float* __restrict__ p, int n) {
    int idx = blockIdx.x * 256 + threadIdx.x;
    if (idx < n) p[idx] = 0.0f;
}

__global__ __launch_bounds__(64) void init_barrier_kernel(unsigned* __restrict__ bar) {
    bar[threadIdx.x] = 0u;   // counter line @0, flag line @32
}

// bu[t][i] = sum_d B[i][d] * u[d][t], fp32, layout [T_LEN][ORDER]. (r6-verified)
__global__ __launch_bounds__(256) void bu_kernel(const float* __restrict__ u,
                                                 const float* __restrict__ Bw,
                                                 float* __restrict__ bu) {
    __shared__ float lds_u[IN_DIM * 64];   // [d][tau_local]
    const int t0 = blockIdx.x * 64;
    const int i0 = blockIdx.y * 256;
    const int tid = threadIdx.x;
    for (int idx = tid; idx < IN_DIM * 64; idx += 256) {
        int d = idx >> 6, tt = idx & 63;
        lds_u[idx] = u[d * T_LEN + t0 + tt];
    }
    __syncthreads();
    const int w = __builtin_amdgcn_readfirstlane(tid >> 6);
    const int l = tid & 63;
    const int ib = i0 + w * 64;           // wave-uniform -> scalar B loads
    float acc[64];
#pragma unroll
    for (int s = 0; s < 64; ++s) acc[s] = 0.0f;
    for (int d = 0; d < IN_DIM; d += 4) {
        float u0 = lds_u[(d + 0) * 64 + l];
        float u1 = lds_u[(d + 1) * 64 + l];
        float u2 = lds_u[(d + 2) * 64 + l];
        float u3 = lds_u[(d + 3) * 64 + l];
#pragma unroll
        for (int s = 0; s < 64; ++s) {
            const float* br = Bw + (size_t)(ib + s) * IN_DIM + d;
            acc[s] += br[0] * u0 + br[1] * u1 + br[2] * u2 + br[3] * u3;
        }
    }
    float* dstp = bu + (size_t)(t0 + l) * ORDER + ib;
#pragma unroll
    for (int q = 0; q < 16; ++q) {
        float4v v = {acc[q * 4 + 0], acc[q * 4 + 1], acc[q * 4 + 2], acc[q * 4 + 3]};
        ((float4v*)dstp)[q] = v;
    }
}

// Pack A (fp32 row-major) into fp16 MFMA A-fragment order (r6-verified):
// ((half8v*)Ap)[R*4096 + c*64 + l] = A[R*16 + (l&15)][c*32 + (l>>4)*8 .. +8].
__global__ __launch_bounds__(256) void pack_kernel(const float* __restrict__ A,
                                                   _Float16* __restrict__ Ap) {
    int tid = blockIdx.x * 256 + threadIdx.x;   // 0 .. 128*64*64-1
    int l = tid & 63;
    int c = (tid >> 6) & 63;
    int R = tid >> 12;
    int row = R * 16 + (l & 15);
    int col = c * 32 + (l >> 4) * 8;
    const float4v* src = (const float4v*)(A + (size_t)row * ORDER + col);
    float4v f0 = src[0], f1 = src[1];
    half8v h;
    h[0] = (_Float16)f0[0]; h[1] = (_Float16)f0[1];
    h[2] = (_Float16)f0[2]; h[3] = (_Float16)f0[3];
    h[4] = (_Float16)f1[0]; h[5] = (_Float16)f1[1];
    h[6] = (_Float16)f1[2]; h[7] = (_Float16)f1[3];
    ((half8v*)Ap)[tid] = h;
}

// Fence-free flat grid barrier (r6-verified). Monotone counter+flag, all
// RELAXED agent-scope (RMWs execute at the MALL). Ordering: __syncthreads
// drains vmcnt, so every wave's H exchanges are at the MALL before arrival.
static __device__ __forceinline__ void grid_barrier(unsigned* __restrict__ bar,
                                                    unsigned want) {
    __syncthreads();
    if (threadIdx.x == 0) {
        unsigned old = __hip_atomic_fetch_add(&bar[0], 1u, __ATOMIC_RELAXED,
                                              __HIP_MEMORY_SCOPE_AGENT);
        if (old + 1u == want * NWG) {
            (void)__hip_atomic_exchange(&bar[32], want, __ATOMIC_RELAXED,
                                        __HIP_MEMORY_SCOPE_AGENT);
        } else {
            while (__hip_atomic_load(&bar[32], __ATOMIC_RELAXED,
                                     __HIP_MEMORY_SCOPE_AGENT) < want)
                __builtin_amdgcn_s_sleep(1);
        }
        __atomic_signal_fence(__ATOMIC_ACQUIRE);
    }
    __syncthreads();
}

// One scan step (r6-verified body). SEG >= 0: also record tanh output into
// the statically-indexed fp16-pair register buffer oreg[4][4] at slot SEG.
template<int SEG>
static __device__ __forceinline__ void do_step(
        int k, bool last,
        const half8v* __restrict__ apb, const float* __restrict__ bu,
        _Float16* __restrict__ Ha, _Float16* __restrict__ Hb,
        unsigned* __restrict__ bar, ull* __restrict__ lds_h,
        int tid, int l, int jg, int j, int mrow, int granH,
        unsigned (&oreg)[4][4]) {
    const ull* __restrict__ src = ((const ull*)((k & 1) ? Hb : Ha)) + jg * 8192;
    ull* __restrict__ dst       = ((ull*)((k & 1) ? Ha : Hb)) + jg * 8192;

    float4v acc0 = {0.f, 0.f, 0.f, 0.f};
    float4v acc1 = {0.f, 0.f, 0.f, 0.f};

#pragma unroll
    for (int half = 0; half < 2; ++half) {
        // Stage 32 KB (K-chunks half*32 .. +32): linear coalesced copy from
        // the coherent point (agent-scope = L2-bypass loads).
        const ull* __restrict__ sh = src + half * 4096;
#pragma unroll 4
        for (int q = 0; q < 16; ++q) {
            int g = q * 256 + tid;
            lds_h[g] = __hip_atomic_load(sh + g, __ATOMIC_RELAXED,
                                         __HIP_MEMORY_SCOPE_AGENT);
        }
        __syncthreads();

        // 32 MFMAs over this K-half (A from L2, B from LDS).
        const half8v* __restrict__ lb = ((const half8v*)lds_h) + l;
        const half8v* __restrict__ ap = apb + half * 32 * 64;
#pragma unroll 8
        for (int c = 0; c < 32; ++c) {
            half8v av = ap[c * 64];      // global 16-B coalesced (L2 hit)
            half8v bv = lb[c * 64];      // ds_read_b128, conflict-free
            if (c & 1) acc1 = __builtin_amdgcn_mfma_f32_16x16x32_f16(av, bv, acc1, 0, 0, 0);
            else       acc0 = __builtin_amdgcn_mfma_f32_16x16x32_f16(av, bv, acc0, 0, 0, 0);
        }
        __syncthreads();                 // LDS reused next half / next step
    }
    float4v hs = acc0 + acc1;

    // Epilogue: h = A*h + bu_t (C-layout: col j = lane&15, row = quad*4+r).
    const int t = j * CLEN - WARM + k;
    float4v bv4;
    if (t >= 0) {
        bv4 = *(const float4v*)(bu + (size_t)t * ORDER + mrow);  // plain, L2
    } else {
        float v = (t == -1) ? 1.0f : 0.0f;   // bu_{-1}=1 injects h0=1 exactly
        bv4 = {v, v, v, v};
    }
    float4v h = hs + bv4;

    // Next state: atomic EXCHANGE (RMW at the MALL -> cross-XCD coherent).
    union { half4v hh; ull u; } cv;
    cv.hh[0] = (_Float16)h[0]; cv.hh[1] = (_Float16)h[1];
    cv.hh[2] = (_Float16)h[2]; cv.hh[3] = (_Float16)h[3];
    (void)__hip_atomic_exchange(dst + granH, cv.u, __ATOMIC_RELAXED,
                                __HIP_MEMORY_SCOPE_AGENT);

    // Record tanh output into registers (static slot SEG; flushed per octave).
    if (SEG >= 0) {
#pragma unroll
        for (int r = 0; r < 4; ++r) {
            float x = h[r];
            float e = __expf(-2.0f * fabsf(x));
            float o = copysignf((1.0f - e) / (1.0f + e), x);
            unsigned hu = (unsigned)__half_as_ushort(__float2half_rn(o));
            if (SEG & 1) oreg[r][SEG >> 1] = (oreg[r][SEG >> 1] & 0xFFFFu) | (hu << 16);
            else         oreg[r][SEG >> 1] = hu;
        }
    }

    if (!last) grid_barrier(bar, (unsigned)(k + 1));
}

// Persistent step kernel (r6 structure; phase B adds register out-buffering).
// Tiling: 128 row-blocks (16 rows) x 8 j-groups (16 chunks); wg = 4 waves =
// 4 consecutive row-blocks sharing an LDS-staged j-panel (2 x 32 KB halves).
// H: 8-B agent-scope atomic exchange stores / agent-scope staged loads.
// Outputs: fp16 pairs in registers, flushed every 8 steps as 32-B sectors.
__global__ __launch_bounds__(256) void step_kernel(const _Float16* __restrict__ Ap,
                                                   const float* __restrict__ bu,
                                                   _Float16* __restrict__ Ha,
                                                   _Float16* __restrict__ Hb,
                                                   float* __restrict__ out,
                                                   unsigned* __restrict__ bar) {
    const int w    = blockIdx.x;         // 0..255
    const int xcd  = w & 7;              // MI355X blockIdx%8 -> XCD (perf only)
    const int idx  = w >> 3;             // 0..31
    const int rg   = xcd * 4 + (idx & 3);// 64-row group: 256-row slab per XCD
    const int jg   = idx >> 2;           // 0..7: 16-chunk j-panel
    const int tid  = threadIdx.x;
    const int wave = tid >> 6;           // 0..3 -> row-block within group
    const int l    = tid & 63;
    const int n    = l & 15;
    const int quad = l >> 4;
    const int R    = rg * 4 + wave;      // global 16-row block, 0..127
    const int i0   = R * 16;
    const int j    = jg * 16 + n;        // this lane's chunk id
    const int mrow = i0 + quad * 4;

    __shared__ ull lds_h[4096];          // 32 KB (exact r6-proven LDS profile)

    // A fragments for this wave (coalesced 16-B loads, L2-resident).
    const half8v* __restrict__ apb = ((const half8v*)Ap) + (size_t)R * 4096 + l;

    // H-store granule within panel jg (B-fragment order, r6-verified).
    const int granH = (((mrow >> 5) * 64) + (((mrow >> 3) & 3) * 16) + n) * 2
                    + ((mrow >> 2) & 1);

    unsigned oreg[4][4];                 // 4 rows x 8 t-segments (fp16 pairs)

    // Phase A: warmup steps k = 0..30 (no output emitted).
    for (int k = 0; k < WARM - 1; ++k)
        do_step<-1>(k, false, apb, bu, Ha, Hb, bar, lds_h,
                    tid, l, jg, j, mrow, granH, oreg);

    // Phase B: 4 octaves x 8 steps, k = 31..62; flush registers per octave.
    for (int g = 0; g < 4; ++g) {
        const int k0 = WARM - 1 + g * 8;
        const bool lg = (g == 3);
        do_step<0>(k0 + 0, false, apb, bu, Ha, Hb, bar, lds_h, tid, l, jg, j, mrow, granH, oreg);
        do_step<1>(k0 + 1, false, apb, bu, Ha, Hb, bar, lds_h, tid, l, jg, j, mrow, granH, oreg);
        do_step<2>(k0 + 2, false, apb, bu, Ha, Hb, bar, lds_h, tid, l, jg, j, mrow, granH, oreg);
        do_step<3>(k0 + 3, false, apb, bu, Ha, Hb, bar, lds_h, tid, l, jg, j, mrow, granH, oreg);
        do_step<4>(k0 + 4, false, apb, bu, Ha, Hb, bar, lds_h, tid, l, jg, j, mrow, granH, oreg);
        do_step<5>(k0 + 5, false, apb, bu, Ha, Hb, bar, lds_h, tid, l, jg, j, mrow, granH, oreg);
        do_step<6>(k0 + 6, false, apb, bu, Ha, Hb, bar, lds_h, tid, l, jg, j, mrow, granH, oreg);
        do_step<7>(k0 + 7, lg,    apb, bu, Ha, Hb, bar, lds_h, tid, l, jg, j, mrow, granH, oreg);

        // Flush octave g: rows mrow..mrow+3, t = j*32 + g*8 .. +8 (32-B sectors,
        // consecutive n-lanes -> consecutive 128-B lines of the same row).
        float* __restrict__ ob = out + (size_t)mrow * T_LEN + j * 32 + g * 8;
#pragma unroll
        for (int r = 0; r < 4; ++r) {
            float4v f0, f1;
#pragma unroll
            for (int p = 0; p < 2; ++p) {
                unsigned v0 = oreg[r][p * 2 + 0];
                unsigned v1 = oreg[r][p * 2 + 1];
                float a0 = __half2float(__ushort_as_half((ushort)(v0 & 0xFFFFu)));
                float a1 = __half2float(__ushort_as_half((ushort)(v0 >> 16)));
                float a2 = __half2float(__ushort_as_half((ushort)(v1 & 0xFFFFu)));
                float a3 = __half2float(__ushort_as_half((ushort)(v1 >> 16)));
                if (p == 0) f0 = {a0, a1, a2, a3};
                else        f1 = {a0, a1, a2, a3};
            }
            *(float4v*)(ob + (size_t)r * T_LEN)     = f0;
            *(float4v*)(ob + (size_t)r * T_LEN + 4) = f1;
        }
    }
}

extern "C" void kernel_launch(void* const* d_in, const int* in_sizes, int n_in,
                              void* d_out, int out_size, void* d_ws, size_t ws_size,
                              hipStream_t stream) {
    const float* u  = (const float*)d_in[0];   // [IN_DIM][T_LEN]
    const float* A  = (const float*)d_in[1];   // [ORDER][ORDER]
    const float* Bw = (const float*)d_in[2];   // [ORDER][IN_DIM]
    float* out = (float*)d_out;                // [ORDER][T_LEN]

    char* ws = (char*)d_ws;
    float*     bu  = (float*)ws;                                 // 33,554,432 B
    _Float16*  Ap  = (_Float16*)(ws + 33554432);                 //  8,388,608 B
    _Float16*  Ha  = (_Float16*)(ws + 41943040);                 //    524,288 B
    _Float16*  Hb  = (_Float16*)(ws + 42467328);                 //    524,288 B
    unsigned*  bar = (unsigned*)(ws + 42991616);                 //        256 B

    // H_0 = zeros in Ha (ws is poisoned 0xAA before every call).
    zero_kernel<<<dim3(512), 256, 0, stream>>>((float*)Ha, NCHUNK * ORDER / 2);
    init_barrier_kernel<<<dim3(1), 64, 0, stream>>>(bar);
    bu_kernel<<<dim3(64, 8), 256, 0, stream>>>(u, Bw, bu);
    pack_kernel<<<dim3(2048), 256, 0, stream>>>(A, Ap);

    void* args[] = {(void*)&Ap, (void*)&bu, (void*)&Ha, (void*)&Hb,
                    (void*)&out, (void*)&bar};
    hipLaunchCooperativeKernel((void*)step_kernel, dim3(NWG), dim3(256), args, 0, stream);
}